// Round 1
// baseline (163.919 us; speedup 1.0000x reference)
//
#include <hip/hip_runtime.h>

// WindowOverlapProcessor: gather formulation.
// Regular grid: window n covers rows [8*(n/63), 8*(n/63)+16) etc.
// Each output pixel (b,h,w) is covered by <=2x2 windows; sum their
// gaussian-blend-weighted contributions and divide by the weight sum.
// Traffic: read 97.5 MB windows exactly once + write 25.2 MB out.

#define OH 512
#define OW 512
#define NB 8
#define NC 3
#define WSZ 16
#define STR 8
#define HWIN 63
#define NWIN (63 * 63)

__global__ __launch_bounds__(256) void window_overlap_kernel(
    const float* __restrict__ win, float* __restrict__ out) {
    // normalized gaussian blend g[16] in LDS (sigma = 16/4 = 4)
    __shared__ float gs[16];
    const int tid = threadIdx.x;
    if (tid < 16) {
        float x = (float)tid - 7.5f;
        gs[tid] = expf(-(x * x) * (1.0f / 32.0f));
    }
    __syncthreads();
    if (tid == 0) {
        float s = 0.0f;
#pragma unroll
        for (int i = 0; i < 16; ++i) s += gs[i];
        float inv = 1.0f / s;
#pragma unroll
        for (int i = 0; i < 16; ++i) gs[i] *= inv;
    }
    __syncthreads();

    const int idx = blockIdx.x * 256 + tid;   // grid sized exactly B*H*W
    const int w = idx & (OW - 1);
    const int h = (idx >> 9) & (OH - 1);
    const int b = idx >> 18;

    // covering window rows i: i*8 <= h <= i*8+15
    // ceil((h-15)/8) == floor((h-8)/8); arithmetic >> gives floor.
    const int ilo = max((h - 8) >> 3, 0);
    const int ihi = min(h >> 3, HWIN - 1);
    const int jlo = max((w - 8) >> 3, 0);
    const int jhi = min(w >> 3, HWIN - 1);

    float acc0 = 0.0f, acc1 = 0.0f, acc2 = 0.0f, wsum = 0.0f;
    for (int i = ilo; i <= ihi; ++i) {
        const int dh = h - i * STR;
        const float gh = gs[dh];               // wave-uniform broadcast
        const int rowbase = (b * NWIN + i * HWIN) * (WSZ * WSZ) + dh * WSZ;
        for (int j = jlo; j <= jhi; ++j) {
            const int dw = w - j * STR;
            const float g = gh * gs[dw];
            const int base = (rowbase + j * (WSZ * WSZ) + dw) * NC;
            acc0 += g * win[base + 0];
            acc1 += g * win[base + 1];
            acc2 += g * win[base + 2];
            wsum += g;
        }
    }

    const float r = 1.0f / (wsum + 1e-8f);
    const int p = h * OW + w;
    float* ob = out + (size_t)b * NC * (OH * OW);
    ob[p] = acc0 * r;
    ob[OH * OW + p] = acc1 * r;
    ob[2 * OH * OW + p] = acc2 * r;
}

extern "C" void kernel_launch(void* const* d_in, const int* in_sizes, int n_in,
                              void* d_out, int out_size, void* d_ws, size_t ws_size,
                              hipStream_t stream) {
    const float* windows = (const float*)d_in[0];
    float* out = (float*)d_out;
    const int total = NB * OH * OW;            // 2,097,152 threads
    window_overlap_kernel<<<total / 256, 256, 0, stream>>>(windows, out);
}